// Round 12
// baseline (189.640 us; speedup 1.0000x reference)
//
#include <hip/hip_runtime.h>

#define NN 150000
#define EE 600000
#define INC 64
#define HC 128
#define OC 10
#define BSZ 50000

typedef long long ll;
typedef _Float16 f16;
typedef __attribute__((ext_vector_type(8))) short short8v;
typedef __attribute__((ext_vector_type(8))) _Float16 f16x8;
typedef __attribute__((ext_vector_type(4))) float f32x4;

__device__ __forceinline__ float h2f(ushort u) {
  f16 h;
  __builtin_memcpy(&h, &u, 2);
  return (float)h;
}
__device__ __forceinline__ ushort f2h(float f) {
  f16 h = (f16)f;
  ushort u;
  __builtin_memcpy(&u, &h, 2);
  return u;
}

// ---------- merged: zero cnt + weight prep (fp16 transpose; Wc2 padded to 16 cols) ----------
__global__ __launch_bounds__(256) void k_prep(const float* __restrict__ W1,
                                              const float* __restrict__ W2,
                                              const float* __restrict__ Wc1,
                                              const float* __restrict__ Wc2,
                                              ushort* t1h, ushort* t2h, ushort* tch,
                                              ushort* t2ch, int* cnt) {
  int t = blockIdx.x * 256 + threadIdx.x;
  if (t < 150016) { cnt[t] = 0; return; }
  t -= 150016;
  if (t < (64 + 128 + 384) * 128) {
    const float* W; ushort* th; int K, idx;
    if (t < 64 * 128)              { W = W1;  th = t1h; K = 64;  idx = t; }
    else if (t < (64 + 128) * 128) { W = W2;  th = t2h; K = 128; idx = t - 64 * 128; }
    else                           { W = Wc1; th = tch; K = 384; idx = t - (64 + 128) * 128; }
    int col = idx & 127;
    int k = idx >> 7;
    th[(ll)col * K + k] = f2h(W[(ll)k * 128 + col]);
  } else if (t < (64 + 128 + 384) * 128 + 16 * 128) {
    int idx = t - (64 + 128 + 384) * 128;   // 0..2047
    int col = idx >> 7;                     // 0..15
    int k = idx & 127;
    float v = (col < OC) ? Wc2[(ll)k * OC + col] : 0.f;
    t2ch[col * 128 + k] = f2h(v);
  }
}

// count + per-edge slot in one pass (slot write coalesced)
__global__ __launch_bounds__(256) void k_count(const int* __restrict__ col, int* cnt,
                                               int* __restrict__ slot, int e) {
  int i = blockIdx.x * 256 + threadIdx.x;
  if (i < e) slot[i] = atomicAdd(&cnt[col[i]], 1);
}

__global__ __launch_bounds__(256) void k_scan1(const int* __restrict__ cnt, int* ex, int* bsum,
                                               float* __restrict__ dis, int n) {
  __shared__ int s[256];
  const int t = threadIdx.x;
  const int base = blockIdx.x * 1024 + t * 4;
  int v[4], tot = 0;
#pragma unroll
  for (int i = 0; i < 4; ++i) {
    v[i] = (base + i < n) ? cnt[base + i] : 0;
    tot += v[i];
    if (base + i < n) dis[base + i] = rsqrtf((float)(1 + v[i]));
  }
  s[t] = tot;
  __syncthreads();
#pragma unroll
  for (int off = 1; off < 256; off <<= 1) {
    int x = (t >= off) ? s[t - off] : 0;
    __syncthreads();
    s[t] += x;
    __syncthreads();
  }
  int run = s[t] - tot;
#pragma unroll
  for (int i = 0; i < 4; ++i) {
    if (base + i < n) ex[base + i] = run;
    run += v[i];
  }
  if (t == 255) bsum[blockIdx.x] = s[255];
}

// merged scan2+scan3: each block scans all block-sums in LDS, adds its exclusive prefix
__global__ __launch_bounds__(256) void k_scan23(int* rp, const int* __restrict__ bsum,
                                                int n, int e, int nb) {
  __shared__ int s[256];
  const int t = threadIdx.x;
  int v = (t < nb) ? bsum[t] : 0;
  s[t] = v;
  __syncthreads();
#pragma unroll
  for (int off = 1; off < 256; off <<= 1) {
    int x = (t >= off) ? s[t - off] : 0;
    __syncthreads();
    s[t] += x;
    __syncthreads();
  }
  const int off = (blockIdx.x == 0) ? 0 : s[blockIdx.x - 1];  // exclusive prefix of this block
  const int base = blockIdx.x * 1024 + t * 4;
#pragma unroll
  for (int i = 0; i < 4; ++i)
    if (base + i < n) rp[base + i] += off;
  if (blockIdx.x == 0 && t == 0) rp[n] = e;
}

// csr[rp[c] + slot[i]] = row  (no atomic: slot precomputed)
__global__ __launch_bounds__(256) void k_fill_csr(const int* __restrict__ ei,
                                                  const int* __restrict__ rp,
                                                  const int* __restrict__ slot,
                                                  int* csr, int e) {
  int i = blockIdx.x * 256 + threadIdx.x;
  if (i >= e) return;
  int r = ei[i];
  int c = ei[EE + i];
  csr[rp[c] + slot[i]] = r;
}

// ---------- MFMA GEMM (f16 direct): Y[nrows][128] = X[nrows][K] @ W[K][128] ----------
// A fp16 exact, B fp16, fp32 accumulate via mfma_f32_16x16x32_f16.
// ASRC 0: X fp32 (convert in-register). ASRC 2: X fp16 (pure copy staging).
// MODE 1: Y16 = fp16( dis[row] * Y ).  MODE 4: Y16 = fp16(relu(Y+bias)).
template<int K, int ASRC, int MODE>
__global__ __launch_bounds__(256) void k_gemm(const float* __restrict__ Xf,
                                              const ushort* __restrict__ Xh16,
                                              const ushort* __restrict__ Wth,
                                              const float* __restrict__ bias,
                                              const float* __restrict__ dis,
                                              ushort* __restrict__ Y16, int nrows) {
  __shared__ ushort sA[128][40];
  __shared__ ushort sB[128][40];
  const int t = threadIdx.x;
  const int lane = t & 63;
  const int wid = t >> 6;
  const int wr = wid >> 1, wc = wid & 1;
  const int row0 = blockIdx.x * 128;

  f32x4 acc[4][4];
#pragma unroll
  for (int m = 0; m < 4; ++m)
#pragma unroll
    for (int n = 0; n < 4; ++n) acc[m][n] = (f32x4){0.f, 0.f, 0.f, 0.f};

  const int srow = t >> 1;
  const int shalf = t & 1;

  for (int kc = 0; kc < K; kc += 32) {
    __syncthreads();
    // ---- stage A tile (128 rows x 32 k) ----
    if (ASRC == 0) {
      union { ushort u[16]; short8v v[2]; } hu;
      const ll rg = row0 + srow;
      if (rg < nrows) {
        const float4* p = (const float4*)(Xf + rg * K + kc + shalf * 16);
#pragma unroll
        for (int i = 0; i < 4; ++i) {
          float4 v = p[i];
          hu.u[i * 4]     = f2h(v.x);
          hu.u[i * 4 + 1] = f2h(v.y);
          hu.u[i * 4 + 2] = f2h(v.z);
          hu.u[i * 4 + 3] = f2h(v.w);
        }
      } else {
#pragma unroll
        for (int i = 0; i < 16; ++i) hu.u[i] = 0;
      }
      *(short8v*)&sA[srow][shalf * 16] = hu.v[0];
      *(short8v*)&sA[srow][shalf * 16 + 8] = hu.v[1];
    } else {
      short8v h0 = {0,0,0,0,0,0,0,0}, h1 = h0;
      const ll rg = row0 + srow;
      if (rg < nrows) {
        const short8v* p = (const short8v*)(Xh16 + rg * K + kc + shalf * 16);
        h0 = p[0]; h1 = p[1];
      }
      *(short8v*)&sA[srow][shalf * 16] = h0;
      *(short8v*)&sA[srow][shalf * 16 + 8] = h1;
    }
    // ---- stage B tile (fp16) ----
    {
      const short8v* ph = (const short8v*)(Wth + (ll)srow * K + kc + shalf * 16);
      short8v h0 = ph[0], h1 = ph[1];
      *(short8v*)&sB[srow][shalf * 16] = h0;
      *(short8v*)&sB[srow][shalf * 16 + 8] = h1;
    }
    __syncthreads();
    const int kq = (lane >> 4) * 8;
    const int fr = lane & 15;
    f16x8 ah[4], bh[4];
#pragma unroll
    for (int m = 0; m < 4; ++m) {
      const int r = wr * 64 + m * 16 + fr;
      ah[m] = *(const f16x8*)&sA[r][kq];
    }
#pragma unroll
    for (int n = 0; n < 4; ++n) {
      const int c = wc * 64 + n * 16 + fr;
      bh[n] = *(const f16x8*)&sB[c][kq];
    }
#pragma unroll
    for (int m = 0; m < 4; ++m)
#pragma unroll
      for (int n = 0; n < 4; ++n)
        acc[m][n] = __builtin_amdgcn_mfma_f32_16x16x32_f16(ah[m], bh[n], acc[m][n], 0, 0, 0);
  }

#pragma unroll
  for (int m = 0; m < 4; ++m)
#pragma unroll
    for (int q = 0; q < 4; ++q) {
      const int rl = wr * 64 + m * 16 + (lane >> 4) * 4 + q;
      const ll rg = row0 + rl;
      if (rg >= nrows) continue;
      const float ds = (MODE == 1) ? dis[rg] : 0.f;
#pragma unroll
      for (int n = 0; n < 4; ++n) {
        const int col = wc * 64 + n * 16 + (lane & 15);
        float v = acc[m][n][q];
        if (MODE == 1) {
          Y16[rg * HC + col] = f2h(v * ds);
        } else {
          Y16[rg * HC + col] = f2h(fmaxf(v + bias[col], 0.f));
        }
      }
    }
}

// ---------- gather v6: 2 nodes per 16-lane group (8 chains/wave), 8 row loads in flight ----------
// Dummy lanes (>= deg) point at the node's own row (L1-hot); spurious self-adds
// subtracted exactly at the end. node0 always even; NN even => pair always valid.
#define ACC8(A, V) \
  A[0] += h2f((ushort)(V.x & 0xffff)); A[1] += h2f((ushort)(V.x >> 16)); \
  A[2] += h2f((ushort)(V.y & 0xffff)); A[3] += h2f((ushort)(V.y >> 16)); \
  A[4] += h2f((ushort)(V.z & 0xffff)); A[5] += h2f((ushort)(V.z >> 16)); \
  A[6] += h2f((ushort)(V.w & 0xffff)); A[7] += h2f((ushort)(V.w >> 16));

__global__ __launch_bounds__(256) void k_gather(const ushort* __restrict__ xw16,
                                                const int* __restrict__ csr,
                                                const int* __restrict__ rp,
                                                const float* __restrict__ dis,
                                                const float* __restrict__ bias,
                                                ushort* __restrict__ h16, int n) {
  const int node0 = blockIdx.x * 32 + ((threadIdx.x >> 4) << 1);  // 32 nodes / block
  const int lane = threadIdx.x & 63;
  const int sl = lane & 15;
  if (node0 >= n) return;
  const bool has1 = (node0 + 1) < n;           // uniformly true for even n
  const int s0 = rp[node0];
  const int e0 = rp[node0 + 1];
  const int e1 = has1 ? rp[node0 + 2] : e0;
  const int deg0 = e0 - s0;
  const int deg1 = e1 - e0;

  int idx0 = node0;                            // dummy = self row
  int idx1 = has1 ? (node0 + 1) : node0;
  if (sl < deg0) idx0 = csr[s0 + sl];
  if (has1 && sl < deg1) idx1 = csr[e0 + sl];

  const uint4* xwq = (const uint4*)xw16;       // 16 uint4 per row
  const uint4 sv0 = xwq[(ll)node0 * 16 + sl];
  const uint4 sv1 = has1 ? xwq[(ll)(node0 + 1) * 16 + sl] : sv0;

  float a[8], c[8];
  a[0] = h2f((ushort)(sv0.x & 0xffff)); a[1] = h2f((ushort)(sv0.x >> 16));
  a[2] = h2f((ushort)(sv0.y & 0xffff)); a[3] = h2f((ushort)(sv0.y >> 16));
  a[4] = h2f((ushort)(sv0.z & 0xffff)); a[5] = h2f((ushort)(sv0.z >> 16));
  a[6] = h2f((ushort)(sv0.w & 0xffff)); a[7] = h2f((ushort)(sv0.w >> 16));
  c[0] = h2f((ushort)(sv1.x & 0xffff)); c[1] = h2f((ushort)(sv1.x >> 16));
  c[2] = h2f((ushort)(sv1.y & 0xffff)); c[3] = h2f((ushort)(sv1.y >> 16));
  c[4] = h2f((ushort)(sv1.z & 0xffff)); c[5] = h2f((ushort)(sv1.z >> 16));
  c[6] = h2f((ushort)(sv1.w & 0xffff)); c[7] = h2f((ushort)(sv1.w >> 16));

  const int gbase = lane & 48;
  const int df0 = (deg0 < 16) ? deg0 : 16;
  const int df1 = has1 ? ((deg1 < 16) ? deg1 : 16) : 0;
  const int nb0 = (df0 + 3) >> 2;
  const int nb1 = (df1 + 3) >> 2;
  const int nblk = (nb0 > nb1) ? nb0 : nb1;

  for (int b = 0, j = 0; b < nblk; ++b, j += 4) {   // 8 independent row loads per iter
    const int r0 = __shfl(idx0, gbase + j);
    const int r1 = __shfl(idx0, gbase + j + 1);
    const int r2 = __shfl(idx0, gbase + j + 2);
    const int r3 = __shfl(idx0, gbase + j + 3);
    const int q0 = __shfl(idx1, gbase + j);
    const int q1 = __shfl(idx1, gbase + j + 1);
    const int q2 = __shfl(idx1, gbase + j + 2);
    const int q3 = __shfl(idx1, gbase + j + 3);
    const uint4 v0 = xwq[(ll)r0 * 16 + sl];
    const uint4 v1 = xwq[(ll)r1 * 16 + sl];
    const uint4 v2 = xwq[(ll)r2 * 16 + sl];
    const uint4 v3 = xwq[(ll)r3 * 16 + sl];
    const uint4 w0 = xwq[(ll)q0 * 16 + sl];
    const uint4 w1 = xwq[(ll)q1 * 16 + sl];
    const uint4 w2 = xwq[(ll)q2 * 16 + sl];
    const uint4 w3 = xwq[(ll)q3 * 16 + sl];
    ACC8(a, v0) ACC8(a, v1) ACC8(a, v2) ACC8(a, v3)
    ACC8(c, w0) ACC8(c, w1) ACC8(c, w2) ACC8(c, w3)
  }
  // exact removal of dummy self-adds
  {
    const int nd0 = (nblk << 2) - df0;
    if (nd0) {
      const float nd = -(float)nd0;
      a[0] = fmaf(nd, h2f((ushort)(sv0.x & 0xffff)), a[0]);
      a[1] = fmaf(nd, h2f((ushort)(sv0.x >> 16)), a[1]);
      a[2] = fmaf(nd, h2f((ushort)(sv0.y & 0xffff)), a[2]);
      a[3] = fmaf(nd, h2f((ushort)(sv0.y >> 16)), a[3]);
      a[4] = fmaf(nd, h2f((ushort)(sv0.z & 0xffff)), a[4]);
      a[5] = fmaf(nd, h2f((ushort)(sv0.z >> 16)), a[5]);
      a[6] = fmaf(nd, h2f((ushort)(sv0.w & 0xffff)), a[6]);
      a[7] = fmaf(nd, h2f((ushort)(sv0.w >> 16)), a[7]);
    }
    const int nd1 = (nblk << 2) - df1;
    if (has1 && nd1) {
      const float nd = -(float)nd1;
      c[0] = fmaf(nd, h2f((ushort)(sv1.x & 0xffff)), c[0]);
      c[1] = fmaf(nd, h2f((ushort)(sv1.x >> 16)), c[1]);
      c[2] = fmaf(nd, h2f((ushort)(sv1.y & 0xffff)), c[2]);
      c[3] = fmaf(nd, h2f((ushort)(sv1.y >> 16)), c[3]);
      c[4] = fmaf(nd, h2f((ushort)(sv1.z & 0xffff)), c[4]);
      c[5] = fmaf(nd, h2f((ushort)(sv1.z >> 16)), c[5]);
      c[6] = fmaf(nd, h2f((ushort)(sv1.w & 0xffff)), c[6]);
      c[7] = fmaf(nd, h2f((ushort)(sv1.w >> 16)), c[7]);
    }
  }
  // rare spill (deg > 16)
  for (int j = 16; j < deg0; ++j) {
    const uint4 v = xwq[(ll)csr[s0 + j] * 16 + sl];
    ACC8(a, v)
  }
  if (has1)
    for (int j = 16; j < deg1; ++j) {
      const uint4 w = xwq[(ll)csr[e0 + j] * 16 + sl];
      ACC8(c, w)
    }

  const float4* bias4 = (const float4*)bias;
  const float4 b0 = bias4[sl * 2];
  const float4 b1 = bias4[sl * 2 + 1];
  {
    const float dc = dis[node0];
    uint4 o;
    o.x = (uint)f2h(fmaxf(fmaf(dc, a[0], b0.x), 0.f)) | ((uint)f2h(fmaxf(fmaf(dc, a[1], b0.y), 0.f)) << 16);
    o.y = (uint)f2h(fmaxf(fmaf(dc, a[2], b0.z), 0.f)) | ((uint)f2h(fmaxf(fmaf(dc, a[3], b0.w), 0.f)) << 16);
    o.z = (uint)f2h(fmaxf(fmaf(dc, a[4], b1.x), 0.f)) | ((uint)f2h(fmaxf(fmaf(dc, a[5], b1.y), 0.f)) << 16);
    o.w = (uint)f2h(fmaxf(fmaf(dc, a[6], b1.z), 0.f)) | ((uint)f2h(fmaxf(fmaf(dc, a[7], b1.w), 0.f)) << 16);
    ((uint4*)h16)[(ll)node0 * 16 + sl] = o;
  }
  if (has1) {
    const float dc = dis[node0 + 1];
    uint4 o;
    o.x = (uint)f2h(fmaxf(fmaf(dc, c[0], b0.x), 0.f)) | ((uint)f2h(fmaxf(fmaf(dc, c[1], b0.y), 0.f)) << 16);
    o.y = (uint)f2h(fmaxf(fmaf(dc, c[2], b0.z), 0.f)) | ((uint)f2h(fmaxf(fmaf(dc, c[3], b0.w), 0.f)) << 16);
    o.z = (uint)f2h(fmaxf(fmaf(dc, c[4], b1.x), 0.f)) | ((uint)f2h(fmaxf(fmaf(dc, c[5], b1.y), 0.f)) << 16);
    o.w = (uint)f2h(fmaxf(fmaf(dc, c[6], b1.z), 0.f)) | ((uint)f2h(fmaxf(fmaf(dc, c[7], b1.w), 0.f)) << 16);
    ((uint4*)h16)[(ll)(node0 + 1) * 16 + sl] = o;
  }
}

// ---------- MFMA head (f16 direct): logits = z16 @ Wc2 + bc2 ; out = log_softmax ----------
__global__ __launch_bounds__(256) void k_head_mfma(const ushort* __restrict__ Z16,
                                                   const ushort* __restrict__ Wth,
                                                   const float* __restrict__ bc2,
                                                   float* __restrict__ out, int nrows) {
  __shared__ ushort sZ[128][40];
  __shared__ ushort sW[16][132];
  __shared__ float ob[128 * OC];
  const int t = threadIdx.x;
  const int lane = t & 63;
  const int wid = t >> 6;
  const int row0 = blockIdx.x * 128;

  {
    const int col = t >> 4;
    const int k0 = (t & 15) * 8;
    *(short8v*)&sW[col][k0] = *(const short8v*)(Wth + col * 128 + k0);
  }

  f32x4 acc[2];
  acc[0] = (f32x4){0.f, 0.f, 0.f, 0.f};
  acc[1] = (f32x4){0.f, 0.f, 0.f, 0.f};

  const int srow = t >> 1;
  const int shalf = t & 1;

  for (int kc = 0; kc < HC; kc += 32) {
    __syncthreads();
    {
      short8v h0 = {0,0,0,0,0,0,0,0}, h1 = h0;
      const ll rg = row0 + srow;
      if (rg < nrows) {
        const short8v* p = (const short8v*)(Z16 + rg * HC + kc + shalf * 16);
        h0 = p[0]; h1 = p[1];
      }
      *(short8v*)&sZ[srow][shalf * 16] = h0;
      *(short8v*)&sZ[srow][shalf * 16 + 8] = h1;
    }
    __syncthreads();
    const int kq = (lane >> 4) * 8;
    const int fr = lane & 15;
    const f16x8 bh = *(const f16x8*)&sW[fr][kc + kq];
#pragma unroll
    for (int mt = 0; mt < 2; ++mt) {
      const int r = wid * 32 + mt * 16 + fr;
      const f16x8 ah = *(const f16x8*)&sZ[r][kq];
      acc[mt] = __builtin_amdgcn_mfma_f32_16x16x32_f16(ah, bh, acc[mt], 0, 0, 0);
    }
  }

  const int fr = lane & 15;
  const float bcv = (fr < OC) ? bc2[fr] : -1e30f;
#pragma unroll
  for (int mt = 0; mt < 2; ++mt)
#pragma unroll
    for (int q = 0; q < 4; ++q) {
      float a = acc[mt][q] + bcv;
      float mx = a;
#pragma unroll
      for (int m = 8; m; m >>= 1) mx = fmaxf(mx, __shfl_xor(mx, m, 64));
      float ex = expf(a - mx);
#pragma unroll
      for (int m = 8; m; m >>= 1) ex += __shfl_xor(ex, m, 64);
      const float res = a - mx - logf(ex);
      const int rl = wid * 32 + mt * 16 + (lane >> 4) * 4 + q;
      if (fr < OC) ob[rl * OC + fr] = res;
    }
  __syncthreads();
  const int rem = nrows - row0;
  const int cnt = ((rem < 128) ? rem : 128) * OC;
  for (int i = t; i < cnt; i += 256) out[(ll)row0 * OC + i] = ob[i];
}

extern "C" void kernel_launch(void* const* d_in, const int* in_sizes, int n_in,
                              void* d_out, int out_size, void* d_ws, size_t ws_size,
                              hipStream_t stream) {
  const float* x   = (const float*)d_in[0];
  const int*   ei  = (const int*)d_in[1];   // [2][E] int32
  const float* W1  = (const float*)d_in[2];
  const float* b1  = (const float*)d_in[3];
  const float* W2  = (const float*)d_in[4];
  const float* b2  = (const float*)d_in[5];
  const float* Wc1 = (const float*)d_in[6];
  const float* bc1 = (const float*)d_in[7];
  const float* Wc2 = (const float*)d_in[8];
  const float* bc2 = (const float*)d_in[9];
  float* out = (float*)d_out;

  char* ws = (char*)d_ws;
  ushort* xw16 = (ushort*)(ws);                       // xw' fp16 [N][128] 38.4MB ; later z16 [BSZ][128]
  ushort* h16  = (ushort*)(ws + 38400000LL);          // h   fp16 [N][128] 38.4MB
  const ll CSRB = 76800000LL;
  float* dis  = (float*)(ws + CSRB);                  // N floats
  int*   rp   = (int*)  (ws + CSRB + 600064LL);       // N+1
  int*   csr  = (int*)  (ws + CSRB + 1200128LL);      // E
  int*   cnt  = (int*)  (ws + CSRB + 3600128LL);      // 150016
  int*   slot = (int*)  (ws + CSRB + 4200192LL);      // E
  int*   bsum = (int*)  (ws + CSRB + 6600192LL);      // 256
  ushort* Wt1h  = (ushort*)(ws + CSRB + 6601216LL);   // 64*128
  ushort* Wt2h  = (ushort*)(ws + CSRB + 6617600LL);   // 128*128
  ushort* Wtc1h = (ushort*)(ws + CSRB + 6650368LL);   // 384*128
  ushort* Wtc2h = (ushort*)(ws + CSRB + 6748672LL);   // 16*128 ; end ~83.5MB

  const int nb = (NN + 1023) / 1024;                  // 147 scan blocks

  // prep (zero cnt + weight transpose) ; CSR build
  k_prep<<<(150016 + (64 + 128 + 384 + 16) * 128 + 255) / 256, 256, 0, stream>>>(
      W1, W2, Wc1, Wc2, Wt1h, Wt2h, Wtc1h, Wtc2h, cnt);
  k_count<<<(EE + 255) / 256, 256, 0, stream>>>(ei + EE, cnt, slot, EE);
  k_scan1<<<nb, 256, 0, stream>>>(cnt, rp, bsum, dis, NN);
  k_scan23<<<nb, 256, 0, stream>>>(rp, bsum, NN, EE, nb);
  k_fill_csr<<<(EE + 255) / 256, 256, 0, stream>>>(ei, rp, slot, csr, EE);

  // layer 1: xw' = fp16(dis.row * (x @ W1))
  k_gemm<INC, 0, 1><<<(NN + 127) / 128, 256, 0, stream>>>(x, nullptr, Wt1h, nullptr, dis, xw16, NN);
  k_gather<<<(NN + 31) / 32, 256, 0, stream>>>(xw16, csr, rp, dis, b1, h16, NN);

  // layer 2: xw' = fp16(dis.row * (h @ W2))
  k_gemm<HC, 2, 1><<<(NN + 127) / 128, 256, 0, stream>>>(nullptr, h16, Wt2h, nullptr, dis, xw16, NN);
  k_gather<<<(NN + 31) / 32, 256, 0, stream>>>(xw16, csr, rp, dis, b2, h16, NN);

  // classifier: z16 = fp16(relu(flat @ Wc1 + bc1)), flat = h16 viewed [BSZ][384]; z16 reuses xw16
  k_gemm<3 * HC, 2, 4><<<(BSZ + 127) / 128, 256, 0, stream>>>(nullptr, h16, Wtc1h, bc1, nullptr, xw16, BSZ);

  // head: out = log_softmax(z16 @ Wc2 + bc2)
  k_head_mfma<<<(BSZ + 127) / 128, 256, 0, stream>>>(xw16, Wtc2h, bc2, out, BSZ);
}

// Round 13
// 184.199 us; speedup vs baseline: 1.0295x; 1.0295x over previous
//
#include <hip/hip_runtime.h>

#define NN 150000
#define EE 600000
#define INC 64
#define HC 128
#define OC 10
#define BSZ 50000

typedef long long ll;
typedef _Float16 f16;
typedef __attribute__((ext_vector_type(8))) short short8v;
typedef __attribute__((ext_vector_type(8))) _Float16 f16x8;
typedef __attribute__((ext_vector_type(4))) float f32x4;

__device__ __forceinline__ float h2f(ushort u) {
  f16 h;
  __builtin_memcpy(&h, &u, 2);
  return (float)h;
}
__device__ __forceinline__ ushort f2h(float f) {
  f16 h = (f16)f;
  ushort u;
  __builtin_memcpy(&u, &h, 2);
  return u;
}

// ---------- merged: zero cnt + weight prep (fp16 transpose; Wc2 padded to 16 cols) ----------
__global__ __launch_bounds__(256) void k_prep(const float* __restrict__ W1,
                                              const float* __restrict__ W2,
                                              const float* __restrict__ Wc1,
                                              const float* __restrict__ Wc2,
                                              ushort* t1h, ushort* t2h, ushort* tch,
                                              ushort* t2ch, int* cnt) {
  int t = blockIdx.x * 256 + threadIdx.x;
  if (t < 150016) { cnt[t] = 0; return; }
  t -= 150016;
  if (t < (64 + 128 + 384) * 128) {
    const float* W; ushort* th; int K, idx;
    if (t < 64 * 128)              { W = W1;  th = t1h; K = 64;  idx = t; }
    else if (t < (64 + 128) * 128) { W = W2;  th = t2h; K = 128; idx = t - 64 * 128; }
    else                           { W = Wc1; th = tch; K = 384; idx = t - (64 + 128) * 128; }
    int col = idx & 127;
    int k = idx >> 7;
    th[(ll)col * K + k] = f2h(W[(ll)k * 128 + col]);
  } else if (t < (64 + 128 + 384) * 128 + 16 * 128) {
    int idx = t - (64 + 128 + 384) * 128;   // 0..2047
    int col = idx >> 7;                     // 0..15
    int k = idx & 127;
    float v = (col < OC) ? Wc2[(ll)k * OC + col] : 0.f;
    t2ch[col * 128 + k] = f2h(v);
  }
}

// count + per-edge slot in one pass (slot write coalesced)
__global__ __launch_bounds__(256) void k_count(const int* __restrict__ col, int* cnt,
                                               int* __restrict__ slot, int e) {
  int i = blockIdx.x * 256 + threadIdx.x;
  if (i < e) slot[i] = atomicAdd(&cnt[col[i]], 1);
}

__global__ __launch_bounds__(256) void k_scan1(const int* __restrict__ cnt, int* ex, int* bsum,
                                               float* __restrict__ dis, int n) {
  __shared__ int s[256];
  const int t = threadIdx.x;
  const int base = blockIdx.x * 1024 + t * 4;
  int v[4], tot = 0;
#pragma unroll
  for (int i = 0; i < 4; ++i) {
    v[i] = (base + i < n) ? cnt[base + i] : 0;
    tot += v[i];
    if (base + i < n) dis[base + i] = rsqrtf((float)(1 + v[i]));
  }
  s[t] = tot;
  __syncthreads();
#pragma unroll
  for (int off = 1; off < 256; off <<= 1) {
    int x = (t >= off) ? s[t - off] : 0;
    __syncthreads();
    s[t] += x;
    __syncthreads();
  }
  int run = s[t] - tot;
#pragma unroll
  for (int i = 0; i < 4; ++i) {
    if (base + i < n) ex[base + i] = run;
    run += v[i];
  }
  if (t == 255) bsum[blockIdx.x] = s[255];
}

// merged scan2+scan3: each block scans all block-sums in LDS, adds its exclusive prefix
__global__ __launch_bounds__(256) void k_scan23(int* rp, const int* __restrict__ bsum,
                                                int n, int e, int nb) {
  __shared__ int s[256];
  const int t = threadIdx.x;
  int v = (t < nb) ? bsum[t] : 0;
  s[t] = v;
  __syncthreads();
#pragma unroll
  for (int off = 1; off < 256; off <<= 1) {
    int x = (t >= off) ? s[t - off] : 0;
    __syncthreads();
    s[t] += x;
    __syncthreads();
  }
  const int off = (blockIdx.x == 0) ? 0 : s[blockIdx.x - 1];  // exclusive prefix of this block
  const int base = blockIdx.x * 1024 + t * 4;
#pragma unroll
  for (int i = 0; i < 4; ++i)
    if (base + i < n) rp[base + i] += off;
  if (blockIdx.x == 0 && t == 0) rp[n] = e;
}

// csr[rp[c] + slot[i]] = row  (no atomic: slot precomputed)
__global__ __launch_bounds__(256) void k_fill_csr(const int* __restrict__ ei,
                                                  const int* __restrict__ rp,
                                                  const int* __restrict__ slot,
                                                  int* csr, int e) {
  int i = blockIdx.x * 256 + threadIdx.x;
  if (i >= e) return;
  int r = ei[i];
  int c = ei[EE + i];
  csr[rp[c] + slot[i]] = r;
}

// ---------- MFMA GEMM (f16 direct): Y[nrows][128] = X[nrows][K] @ W[K][128] ----------
// A fp16 exact, B fp16, fp32 accumulate via mfma_f32_16x16x32_f16.
// ASRC 0: X fp32 (convert in-register). ASRC 2: X fp16 (pure copy staging).
// MODE 1: Y16 = fp16( dis[row] * Y ).  MODE 4: Y16 = fp16(relu(Y+bias)).
template<int K, int ASRC, int MODE>
__global__ __launch_bounds__(256) void k_gemm(const float* __restrict__ Xf,
                                              const ushort* __restrict__ Xh16,
                                              const ushort* __restrict__ Wth,
                                              const float* __restrict__ bias,
                                              const float* __restrict__ dis,
                                              ushort* __restrict__ Y16, int nrows) {
  __shared__ ushort sA[128][40];
  __shared__ ushort sB[128][40];
  const int t = threadIdx.x;
  const int lane = t & 63;
  const int wid = t >> 6;
  const int wr = wid >> 1, wc = wid & 1;
  const int row0 = blockIdx.x * 128;

  f32x4 acc[4][4];
#pragma unroll
  for (int m = 0; m < 4; ++m)
#pragma unroll
    for (int n = 0; n < 4; ++n) acc[m][n] = (f32x4){0.f, 0.f, 0.f, 0.f};

  const int srow = t >> 1;
  const int shalf = t & 1;

  for (int kc = 0; kc < K; kc += 32) {
    __syncthreads();
    // ---- stage A tile (128 rows x 32 k) ----
    if (ASRC == 0) {
      union { ushort u[16]; short8v v[2]; } hu;
      const ll rg = row0 + srow;
      if (rg < nrows) {
        const float4* p = (const float4*)(Xf + rg * K + kc + shalf * 16);
#pragma unroll
        for (int i = 0; i < 4; ++i) {
          float4 v = p[i];
          hu.u[i * 4]     = f2h(v.x);
          hu.u[i * 4 + 1] = f2h(v.y);
          hu.u[i * 4 + 2] = f2h(v.z);
          hu.u[i * 4 + 3] = f2h(v.w);
        }
      } else {
#pragma unroll
        for (int i = 0; i < 16; ++i) hu.u[i] = 0;
      }
      *(short8v*)&sA[srow][shalf * 16] = hu.v[0];
      *(short8v*)&sA[srow][shalf * 16 + 8] = hu.v[1];
    } else {
      short8v h0 = {0,0,0,0,0,0,0,0}, h1 = h0;
      const ll rg = row0 + srow;
      if (rg < nrows) {
        const short8v* p = (const short8v*)(Xh16 + rg * K + kc + shalf * 16);
        h0 = p[0]; h1 = p[1];
      }
      *(short8v*)&sA[srow][shalf * 16] = h0;
      *(short8v*)&sA[srow][shalf * 16 + 8] = h1;
    }
    // ---- stage B tile (fp16) ----
    {
      const short8v* ph = (const short8v*)(Wth + (ll)srow * K + kc + shalf * 16);
      short8v h0 = ph[0], h1 = ph[1];
      *(short8v*)&sB[srow][shalf * 16] = h0;
      *(short8v*)&sB[srow][shalf * 16 + 8] = h1;
    }
    __syncthreads();
    const int kq = (lane >> 4) * 8;
    const int fr = lane & 15;
    f16x8 ah[4], bh[4];
#pragma unroll
    for (int m = 0; m < 4; ++m) {
      const int r = wr * 64 + m * 16 + fr;
      ah[m] = *(const f16x8*)&sA[r][kq];
    }
#pragma unroll
    for (int n = 0; n < 4; ++n) {
      const int c = wc * 64 + n * 16 + fr;
      bh[n] = *(const f16x8*)&sB[c][kq];
    }
#pragma unroll
    for (int m = 0; m < 4; ++m)
#pragma unroll
      for (int n = 0; n < 4; ++n)
        acc[m][n] = __builtin_amdgcn_mfma_f32_16x16x32_f16(ah[m], bh[n], acc[m][n], 0, 0, 0);
  }

#pragma unroll
  for (int m = 0; m < 4; ++m)
#pragma unroll
    for (int q = 0; q < 4; ++q) {
      const int rl = wr * 64 + m * 16 + (lane >> 4) * 4 + q;
      const ll rg = row0 + rl;
      if (rg >= nrows) continue;
      const float ds = (MODE == 1) ? dis[rg] : 0.f;
#pragma unroll
      for (int n = 0; n < 4; ++n) {
        const int col = wc * 64 + n * 16 + (lane & 15);
        float v = acc[m][n][q];
        if (MODE == 1) {
          Y16[rg * HC + col] = f2h(v * ds);
        } else {
          Y16[rg * HC + col] = f2h(fmaxf(v + bias[col], 0.f));
        }
      }
    }
}

// ---------- gather (R11-best): quarter-wave per node; always-4-wide loads with self-row dummies ----------
// Dummy lanes (>= deg) point at the node's own row (L1-hot); the ndum spurious self-adds
// are subtracted exactly at the end. Removes the serial remainder loop for deg%4 != 0.
__global__ __launch_bounds__(256) void k_gather(const ushort* __restrict__ xw16,
                                                const int* __restrict__ csr,
                                                const int* __restrict__ rp,
                                                const float* __restrict__ dis,
                                                const float* __restrict__ bias,
                                                ushort* __restrict__ h16, int n) {
  const int node = blockIdx.x * 16 + (threadIdx.x >> 4);   // 16 nodes / 256-thr block
  const int lane = threadIdx.x & 63;
  const int sl = lane & 15;                                 // sublane in 16-lane group
  if (node >= n) return;
  const int s = rp[node], e = rp[node + 1];
  const int deg = e - s;

  int myidx = node;                       // dummy index = self row (corrected below)
  if (sl < deg) myidx = csr[s + sl];

  const uint4* xwq = (const uint4*)xw16;                    // 16 uint4 per row
  const uint4 sv = xwq[(ll)node * 16 + sl];                 // self term (pre-scaled)
  float a0 = h2f((ushort)(sv.x & 0xffff)), a1 = h2f((ushort)(sv.x >> 16));
  float a2 = h2f((ushort)(sv.y & 0xffff)), a3 = h2f((ushort)(sv.y >> 16));
  float a4 = h2f((ushort)(sv.z & 0xffff)), a5 = h2f((ushort)(sv.z >> 16));
  float a6 = h2f((ushort)(sv.w & 0xffff)), a7 = h2f((ushort)(sv.w >> 16));

  const int gbase = lane & 48;
  const int dfast = (deg < 16) ? deg : 16;
  const int nblk = (dfast + 3) >> 2;
  int j = 0;
  for (int b = 0; b < nblk; ++b, j += 4) {                  // 4 rows always in flight
    const int r0 = __shfl(myidx, gbase + j);
    const int r1 = __shfl(myidx, gbase + j + 1);
    const int r2 = __shfl(myidx, gbase + j + 2);
    const int r3 = __shfl(myidx, gbase + j + 3);
    const uint4 v0 = xwq[(ll)r0 * 16 + sl];
    const uint4 v1 = xwq[(ll)r1 * 16 + sl];
    const uint4 v2 = xwq[(ll)r2 * 16 + sl];
    const uint4 v3 = xwq[(ll)r3 * 16 + sl];
    a0 += (h2f((ushort)(v0.x & 0xffff)) + h2f((ushort)(v1.x & 0xffff)))
        + (h2f((ushort)(v2.x & 0xffff)) + h2f((ushort)(v3.x & 0xffff)));
    a1 += (h2f((ushort)(v0.x >> 16)) + h2f((ushort)(v1.x >> 16)))
        + (h2f((ushort)(v2.x >> 16)) + h2f((ushort)(v3.x >> 16)));
    a2 += (h2f((ushort)(v0.y & 0xffff)) + h2f((ushort)(v1.y & 0xffff)))
        + (h2f((ushort)(v2.y & 0xffff)) + h2f((ushort)(v3.y & 0xffff)));
    a3 += (h2f((ushort)(v0.y >> 16)) + h2f((ushort)(v1.y >> 16)))
        + (h2f((ushort)(v2.y >> 16)) + h2f((ushort)(v3.y >> 16)));
    a4 += (h2f((ushort)(v0.z & 0xffff)) + h2f((ushort)(v1.z & 0xffff)))
        + (h2f((ushort)(v2.z & 0xffff)) + h2f((ushort)(v3.z & 0xffff)));
    a5 += (h2f((ushort)(v0.z >> 16)) + h2f((ushort)(v1.z >> 16)))
        + (h2f((ushort)(v2.z >> 16)) + h2f((ushort)(v3.z >> 16)));
    a6 += (h2f((ushort)(v0.w & 0xffff)) + h2f((ushort)(v1.w & 0xffff)))
        + (h2f((ushort)(v2.w & 0xffff)) + h2f((ushort)(v3.w & 0xffff)));
    a7 += (h2f((ushort)(v0.w >> 16)) + h2f((ushort)(v1.w >> 16)))
        + (h2f((ushort)(v2.w >> 16)) + h2f((ushort)(v3.w >> 16)));
  }
  const int ndum = (nblk << 2) - dfast;                     // spurious self-adds
  if (ndum) {
    const float nd = -(float)ndum;
    a0 = fmaf(nd, h2f((ushort)(sv.x & 0xffff)), a0);
    a1 = fmaf(nd, h2f((ushort)(sv.x >> 16)), a1);
    a2 = fmaf(nd, h2f((ushort)(sv.y & 0xffff)), a2);
    a3 = fmaf(nd, h2f((ushort)(sv.y >> 16)), a3);
    a4 = fmaf(nd, h2f((ushort)(sv.z & 0xffff)), a4);
    a5 = fmaf(nd, h2f((ushort)(sv.z >> 16)), a5);
    a6 = fmaf(nd, h2f((ushort)(sv.w & 0xffff)), a6);
    a7 = fmaf(nd, h2f((ushort)(sv.w >> 16)), a7);
  }
  for (j = 16; j < deg; ++j) {                              // rare spill (deg > 16)
    const uint4 v = xwq[(ll)csr[s + j] * 16 + sl];
    a0 += h2f((ushort)(v.x & 0xffff)); a1 += h2f((ushort)(v.x >> 16));
    a2 += h2f((ushort)(v.y & 0xffff)); a3 += h2f((ushort)(v.y >> 16));
    a4 += h2f((ushort)(v.z & 0xffff)); a5 += h2f((ushort)(v.z >> 16));
    a6 += h2f((ushort)(v.w & 0xffff)); a7 += h2f((ushort)(v.w >> 16));
  }

  const float dc = dis[node];
  const float4* bias4 = (const float4*)bias;
  const float4 b0 = bias4[sl * 2];
  const float4 b1 = bias4[sl * 2 + 1];
  uint4 o;
  o.x = (uint)f2h(fmaxf(fmaf(dc, a0, b0.x), 0.f)) | ((uint)f2h(fmaxf(fmaf(dc, a1, b0.y), 0.f)) << 16);
  o.y = (uint)f2h(fmaxf(fmaf(dc, a2, b0.z), 0.f)) | ((uint)f2h(fmaxf(fmaf(dc, a3, b0.w), 0.f)) << 16);
  o.z = (uint)f2h(fmaxf(fmaf(dc, a4, b1.x), 0.f)) | ((uint)f2h(fmaxf(fmaf(dc, a5, b1.y), 0.f)) << 16);
  o.w = (uint)f2h(fmaxf(fmaf(dc, a6, b1.z), 0.f)) | ((uint)f2h(fmaxf(fmaf(dc, a7, b1.w), 0.f)) << 16);
  ((uint4*)h16)[(ll)node * 16 + sl] = o;
}

// ---------- MFMA head (f16 direct): logits = z16 @ Wc2 + bc2 ; out = log_softmax ----------
__global__ __launch_bounds__(256) void k_head_mfma(const ushort* __restrict__ Z16,
                                                   const ushort* __restrict__ Wth,
                                                   const float* __restrict__ bc2,
                                                   float* __restrict__ out, int nrows) {
  __shared__ ushort sZ[128][40];
  __shared__ ushort sW[16][132];
  __shared__ float ob[128 * OC];
  const int t = threadIdx.x;
  const int lane = t & 63;
  const int wid = t >> 6;
  const int row0 = blockIdx.x * 128;

  {
    const int col = t >> 4;
    const int k0 = (t & 15) * 8;
    *(short8v*)&sW[col][k0] = *(const short8v*)(Wth + col * 128 + k0);
  }

  f32x4 acc[2];
  acc[0] = (f32x4){0.f, 0.f, 0.f, 0.f};
  acc[1] = (f32x4){0.f, 0.f, 0.f, 0.f};

  const int srow = t >> 1;
  const int shalf = t & 1;

  for (int kc = 0; kc < HC; kc += 32) {
    __syncthreads();
    {
      short8v h0 = {0,0,0,0,0,0,0,0}, h1 = h0;
      const ll rg = row0 + srow;
      if (rg < nrows) {
        const short8v* p = (const short8v*)(Z16 + rg * HC + kc + shalf * 16);
        h0 = p[0]; h1 = p[1];
      }
      *(short8v*)&sZ[srow][shalf * 16] = h0;
      *(short8v*)&sZ[srow][shalf * 16 + 8] = h1;
    }
    __syncthreads();
    const int kq = (lane >> 4) * 8;
    const int fr = lane & 15;
    const f16x8 bh = *(const f16x8*)&sW[fr][kc + kq];
#pragma unroll
    for (int mt = 0; mt < 2; ++mt) {
      const int r = wid * 32 + mt * 16 + fr;
      const f16x8 ah = *(const f16x8*)&sZ[r][kq];
      acc[mt] = __builtin_amdgcn_mfma_f32_16x16x32_f16(ah, bh, acc[mt], 0, 0, 0);
    }
  }

  const int fr = lane & 15;
  const float bcv = (fr < OC) ? bc2[fr] : -1e30f;
#pragma unroll
  for (int mt = 0; mt < 2; ++mt)
#pragma unroll
    for (int q = 0; q < 4; ++q) {
      float a = acc[mt][q] + bcv;
      float mx = a;
#pragma unroll
      for (int m = 8; m; m >>= 1) mx = fmaxf(mx, __shfl_xor(mx, m, 64));
      float ex = expf(a - mx);
#pragma unroll
      for (int m = 8; m; m >>= 1) ex += __shfl_xor(ex, m, 64);
      const float res = a - mx - logf(ex);
      const int rl = wid * 32 + mt * 16 + (lane >> 4) * 4 + q;
      if (fr < OC) ob[rl * OC + fr] = res;
    }
  __syncthreads();
  const int rem = nrows - row0;
  const int cnt = ((rem < 128) ? rem : 128) * OC;
  for (int i = t; i < cnt; i += 256) out[(ll)row0 * OC + i] = ob[i];
}

extern "C" void kernel_launch(void* const* d_in, const int* in_sizes, int n_in,
                              void* d_out, int out_size, void* d_ws, size_t ws_size,
                              hipStream_t stream) {
  const float* x   = (const float*)d_in[0];
  const int*   ei  = (const int*)d_in[1];   // [2][E] int32
  const float* W1  = (const float*)d_in[2];
  const float* b1  = (const float*)d_in[3];
  const float* W2  = (const float*)d_in[4];
  const float* b2  = (const float*)d_in[5];
  const float* Wc1 = (const float*)d_in[6];
  const float* bc1 = (const float*)d_in[7];
  const float* Wc2 = (const float*)d_in[8];
  const float* bc2 = (const float*)d_in[9];
  float* out = (float*)d_out;

  char* ws = (char*)d_ws;
  ushort* xw16 = (ushort*)(ws);                       // xw' fp16 [N][128] 38.4MB ; later z16 [BSZ][128]
  ushort* h16  = (ushort*)(ws + 38400000LL);          // h   fp16 [N][128] 38.4MB
  const ll CSRB = 76800000LL;
  float* dis  = (float*)(ws + CSRB);                  // N floats
  int*   rp   = (int*)  (ws + CSRB + 600064LL);       // N+1
  int*   csr  = (int*)  (ws + CSRB + 1200128LL);      // E
  int*   cnt  = (int*)  (ws + CSRB + 3600128LL);      // 150016
  int*   slot = (int*)  (ws + CSRB + 4200192LL);      // E
  int*   bsum = (int*)  (ws + CSRB + 6600192LL);      // 256
  ushort* Wt1h  = (ushort*)(ws + CSRB + 6601216LL);   // 64*128
  ushort* Wt2h  = (ushort*)(ws + CSRB + 6617600LL);   // 128*128
  ushort* Wtc1h = (ushort*)(ws + CSRB + 6650368LL);   // 384*128
  ushort* Wtc2h = (ushort*)(ws + CSRB + 6748672LL);   // 16*128 ; end ~83.5MB

  const int nb = (NN + 1023) / 1024;                  // 147 scan blocks

  // prep (zero cnt + weight transpose) ; CSR build
  k_prep<<<(150016 + (64 + 128 + 384 + 16) * 128 + 255) / 256, 256, 0, stream>>>(
      W1, W2, Wc1, Wc2, Wt1h, Wt2h, Wtc1h, Wtc2h, cnt);
  k_count<<<(EE + 255) / 256, 256, 0, stream>>>(ei + EE, cnt, slot, EE);
  k_scan1<<<nb, 256, 0, stream>>>(cnt, rp, bsum, dis, NN);
  k_scan23<<<nb, 256, 0, stream>>>(rp, bsum, NN, EE, nb);
  k_fill_csr<<<(EE + 255) / 256, 256, 0, stream>>>(ei, rp, slot, csr, EE);

  // layer 1: xw' = fp16(dis.row * (x @ W1))
  k_gemm<INC, 0, 1><<<(NN + 127) / 128, 256, 0, stream>>>(x, nullptr, Wt1h, nullptr, dis, xw16, NN);
  k_gather<<<(NN + 15) / 16, 256, 0, stream>>>(xw16, csr, rp, dis, b1, h16, NN);

  // layer 2: xw' = fp16(dis.row * (h @ W2))
  k_gemm<HC, 2, 1><<<(NN + 127) / 128, 256, 0, stream>>>(nullptr, h16, Wt2h, nullptr, dis, xw16, NN);
  k_gather<<<(NN + 15) / 16, 256, 0, stream>>>(xw16, csr, rp, dis, b2, h16, NN);

  // classifier: z16 = fp16(relu(flat @ Wc1 + bc1)), flat = h16 viewed [BSZ][384]; z16 reuses xw16
  k_gemm<3 * HC, 2, 4><<<(BSZ + 127) / 128, 256, 0, stream>>>(nullptr, h16, Wtc1h, bc1, nullptr, xw16, BSZ);

  // head: out = log_softmax(z16 @ Wc2 + bc2)
  k_head_mfma<<<(BSZ + 127) / 128, 256, 0, stream>>>(xw16, Wtc2h, bc2, out, BSZ);
}